// Round 16
// baseline (131.697 us; speedup 1.0000x reference)
//
#include <hip/hip_runtime.h>

typedef unsigned short u16;
typedef unsigned u32;
typedef u16 u16x8 __attribute__((ext_vector_type(8)));
typedef u16 u16x4 __attribute__((ext_vector_type(4)));
typedef u32 u32x4 __attribute__((ext_vector_type(4)));
typedef __bf16 bf8 __attribute__((ext_vector_type(8)));
typedef float f32x4 __attribute__((ext_vector_type(4)));
typedef float f32x16 __attribute__((ext_vector_type(16)));

__device__ __forceinline__ u16 f2b(float f) {
  unsigned u = __float_as_uint(f);
  u += 0x7FFFu + ((u >> 16) & 1u);   // RNE
  return (u16)(u >> 16);
}
__device__ __forceinline__ float b2f(u16 h) {
  return __uint_as_float(((unsigned)h) << 16);
}
__device__ __forceinline__ bf8 asbf8(u16x8 v) {
  return __builtin_bit_cast(bf8, v);
}
__device__ __forceinline__ void gll16(const u16* g, u16* l) {
  __builtin_amdgcn_global_load_lds(
      (const __attribute__((address_space(1))) unsigned*)(g),
      (__attribute__((address_space(3))) unsigned*)(l), 16, 0, 0);
}
__device__ __forceinline__ u32 cvtpk(float lo, float hi) {
  u32 r;
  asm("v_cvt_pk_bf16_f32 %0, %1, %2" : "=v"(r) : "v"(lo), "v"(hi));
  return r;
}
// v_permlane32_swap_b32 a, b:  a.hi32lanes <-> b.lo32lanes
__device__ __forceinline__ void plswap(u32& a, u32& b) {
  asm("v_permlane32_swap_b32 %0, %1" : "+v"(a), "+v"(b));
}
__device__ __forceinline__ float ex2(float x) {
  return __builtin_amdgcn_exp2f(x);
}
#define MFMA32(A,B,C) __builtin_amdgcn_mfma_f32_32x32x16_bf16(A,B,C,0,0,0)

// ---------------- fused prep: xconv + 4x wtrans in one dispatch ----------

__global__ __launch_bounds__(256) void prep_all(const float* __restrict__ x,
                                                const float* __restrict__ wqp,
                                                const float* __restrict__ wkp,
                                                const float* __restrict__ wvp,
                                                const float* __restrict__ wop,
                                                u16* __restrict__ xb,
                                                u16* __restrict__ wqkvT,
                                                u16* __restrict__ woT) {
  const int bid = blockIdx.x;
  if (bid < 4096) {                    // xconv
    int i = (bid * 256 + threadIdx.x) * 4;
    float4 v = *(const float4*)(x + i);
    u16x4 o;
    o[0] = f2b(v.x); o[1] = f2b(v.y); o[2] = f2b(v.z); o[3] = f2b(v.w);
    *(u16x4*)(xb + i) = o;
    return;
  }
  __shared__ float tile[32][33];
  const float* in; u16* out; int N, bx, by;
  if (bid < 8192)       { int b = bid - 4096;  in = wqp; out = wqkvT;                         N = 2048; bx = b & 63; by = b >> 6; }
  else if (bid < 9216)  { int b = bid - 8192;  in = wkp; out = wqkvT + (size_t)2048 * 2048;   N = 512;  bx = b & 15; by = b >> 4; }
  else if (bid < 10240) { int b = bid - 9216;  in = wvp; out = wqkvT + (size_t)2560 * 2048;   N = 512;  bx = b & 15; by = b >> 4; }
  else                  { int b = bid - 10240; in = wop; out = woT;                           N = 2048; bx = b & 63; by = b >> 6; }
  const int K = 2048;
  int tx = threadIdx.x & 31, ty = threadIdx.x >> 5;
  int n0 = bx * 32, k0 = by * 32;
#pragma unroll
  for (int yy = 0; yy < 32; yy += 8)
    tile[ty + yy][tx] = in[(size_t)(k0 + ty + yy) * N + n0 + tx];
  __syncthreads();
#pragma unroll
  for (int yy = 0; yy < 32; yy += 8)
    out[(size_t)(n0 + ty + yy) * K + k0 + tx] = f2b(tile[tx][ty + yy]);
}

// split-K reduce + RoPE + fused KV fragment repack.
__global__ __launch_bounds__(256) void reduce_qkv(u16* __restrict__ p0,
                                                  const u16* __restrict__ p1,
                                                  u16* __restrict__ Kf,
                                                  u16* __restrict__ Vf,
                                                  const float* __restrict__ cs,
                                                  const float* __restrict__ sn) {
  int idx = blockIdx.x * 256 + threadIdx.x;      // 2048*384
  int s = idx / 384, c8 = (idx % 384) * 8;
  size_t base = (size_t)s * 3072 + c8;
  if (c8 < 2560) {                               // q or k head: RoPE pairs
    int hc = c8 & 63;
    if (hc >= 32) return;                        // partner handles
    u16x8 a0 = *(const u16x8*)(p0 + base);
    u16x8 a1 = *(const u16x8*)(p1 + base);
    u16x8 b0 = *(const u16x8*)(p0 + base + 32);
    u16x8 b1 = *(const u16x8*)(p1 + base + 32);
    u16x8 oa, ob;
#pragma unroll
    for (int e = 0; e < 8; ++e) {
      float va = b2f(a0[e]) + b2f(a1[e]);
      float vb = b2f(b0[e]) + b2f(b1[e]);
      float c1 = cs[s * 64 + hc + e],      s1 = sn[s * 64 + hc + e];
      float c2 = cs[s * 64 + hc + 32 + e], s2 = sn[s * 64 + hc + 32 + e];
      oa[e] = f2b(va * c1 - vb * s1);
      ob[e] = f2b(vb * c2 + va * s2);
    }
    if (c8 < 2048) {                             // Q: back to qkv
      *(u16x8*)(p0 + base)      = oa;
      *(u16x8*)(p0 + base + 32) = ob;
    } else {                                     // K: to fragment-major Kf
      int kh = (c8 - 2048) >> 6;
      int d0 = hc;                               // < 32, multiple of 8
      int b = s >> 5, la = s & 31;
      int j0 = d0 >> 4, hi0 = (d0 >> 3) & 1;
      size_t f0 = ((((size_t)(kh * 64 + b) * 4 + j0) * 2 + hi0) * 32 + la) * 8;
      size_t f1 = ((((size_t)(kh * 64 + b) * 4 + j0 + 2) * 2 + hi0) * 32 + la) * 8;
      *(u16x8*)(Kf + f0) = oa;
      *(u16x8*)(Kf + f1) = ob;
    }
  } else {                                       // V: sum -> Vf fragments
    u16x8 a0 = *(const u16x8*)(p0 + base);
    u16x8 a1 = *(const u16x8*)(p1 + base);
    int c = c8 - 2560;
    int kh = c >> 6, d0 = c & 63;
    int m = d0 >> 5, la0 = d0 & 31;
    int b = s >> 5, s5 = s & 31;
    int jj = s5 >> 4, hi = (s5 >> 3) & 1, e = s5 & 7;
    u16* dst = Vf + (((size_t)(kh * 64 + b) * 4 + m * 2 + jj) * 64 + hi * 32 + la0) * 8 + e;
#pragma unroll
    for (int i = 0; i < 8; ++i)
      dst[i * 8] = f2b(b2f(a0[i]) + b2f(a1[i]));
  }
}

// split-K reduce for out-proj -> f32 d_out
__global__ __launch_bounds__(256) void reduce_out(const u16* __restrict__ p0,
                                                  const u16* __restrict__ p1,
                                                  float* __restrict__ out) {
  int idx = blockIdx.x * 256 + threadIdx.x;      // 2048*256
  size_t base = (size_t)idx * 8;
  u16x8 a0 = *(const u16x8*)(p0 + base);
  u16x8 a1 = *(const u16x8*)(p1 + base);
  float4 lo, hi;
  lo.x = b2f(a0[0]) + b2f(a1[0]); lo.y = b2f(a0[1]) + b2f(a1[1]);
  lo.z = b2f(a0[2]) + b2f(a1[2]); lo.w = b2f(a0[3]) + b2f(a1[3]);
  hi.x = b2f(a0[4]) + b2f(a1[4]); hi.y = b2f(a0[5]) + b2f(a1[5]);
  hi.z = b2f(a0[6]) + b2f(a1[6]); hi.w = b2f(a0[7]) + b2f(a1[7]);
  *(float4*)(out + base)     = lo;
  *(float4*)(out + base + 4) = hi;
}

// ------- split-K GEMM, BK=64, XOR-swizzled LDS ----------------------------

__global__ __launch_bounds__(256) void gemm_sk(const u16* __restrict__ A,
                                               const u16* __restrict__ Bt,
                                               u16* __restrict__ C0,
                                               u16* __restrict__ C1,
                                               int N, int Kfull, int KH) {
  __shared__ __align__(16) u16 As[128 * 64];
  __shared__ __align__(16) u16 Bs[128 * 64];
  const int t = threadIdx.x;
  const int lane = t & 63, wid = t >> 6;
  const int wm = (wid >> 1) * 64, wn = (wid & 1) * 64;
  const int la = lane & 15, lg = lane >> 4;
  const int m0 = blockIdx.y * 128, n0 = blockIdx.x * 128;
  const int kbeg = blockIdx.z * KH;
  u16* C = blockIdx.z ? C1 : C0;

  const int srow0 = wid * 32 + (lane >> 3);
  const int scolsw = (((lane & 7) ^ (lane >> 3))) * 8;   // pre-swizzled col
  const u16* Ap = A + (size_t)(m0 + srow0) * Kfull + kbeg + scolsw;
  const u16* Bp = Bt + (size_t)(n0 + srow0) * Kfull + kbeg + scolsw;
  u16* Adst = &As[wid * 2048];
  u16* Bdst = &Bs[wid * 2048];
  const size_t rstep8 = (size_t)8 * Kfull;

  f32x4 acc[4][4] = {};

  for (int k0 = 0; k0 < KH; k0 += 64) {
    __syncthreads();
#pragma unroll
    for (int cc = 0; cc < 4; ++cc)
      gll16(Ap + k0 + cc * rstep8, Adst + cc * 512);
#pragma unroll
    for (int cc = 0; cc < 4; ++cc)
      gll16(Bp + k0 + cc * rstep8, Bdst + cc * 512);
    __syncthreads();
#pragma unroll
    for (int kk = 0; kk < 2; ++kk) {
      bf8 af[4], bfr[4];
#pragma unroll
      for (int i = 0; i < 4; ++i) {
        const int row = wm + i * 16 + la;
        const int c8 = (kk * 4 + lg) ^ (row & 7);
        af[i] = asbf8(*(const u16x8*)(&As[row * 64 + c8 * 8]));
      }
#pragma unroll
      for (int j = 0; j < 4; ++j) {
        const int row = wn + j * 16 + la;
        const int c8 = (kk * 4 + lg) ^ (row & 7);
        bfr[j] = asbf8(*(const u16x8*)(&Bs[row * 64 + c8 * 8]));
      }
      __builtin_amdgcn_s_setprio(1);
#pragma unroll
      for (int i = 0; i < 4; ++i)
#pragma unroll
        for (int j = 0; j < 4; ++j)
          acc[i][j] = __builtin_amdgcn_mfma_f32_16x16x32_bf16(af[i], bfr[j],
                                                              acc[i][j], 0, 0, 0);
      __builtin_amdgcn_s_setprio(0);
    }
  }

#pragma unroll
  for (int i = 0; i < 4; ++i)
#pragma unroll
    for (int j = 0; j < 4; ++j)
#pragma unroll
      for (int r = 0; r < 4; ++r) {
        int row = m0 + wm + i * 16 + lg * 4 + r;
        int col = n0 + wn + j * 16 + la;
        C[(size_t)row * N + col] = f2b(acc[i][j][r]);
      }
}

// --- flash attention: balanced 2-pass blocks, triple-buffer, 1 barrier ----
// Block = (head, pair pid): pass 0 = q-tile pid, pass 1 = q-tile 31-pid ->
// every block runs exactly 33 kv-group iterations (zero imbalance).
// Within a pass: 4 waves = 2 q-subtiles x 2 kv-halves; per iter ONE
// s_barrier (triple-buffered staging makes the WAR barrier unnecessary).
// Static-max softmax (P = 2^s, shift cancels in o/l); 2-half LDS-sum merge.

#define STEPL(buf, bb) do {                                          \
    const u16* p_ = &smem[(h2 * 3 + (buf)) * 4096 + lane8];          \
    bf8 K0 = asbf8(*(const u16x8*)(p_));                             \
    bf8 K1 = asbf8(*(const u16x8*)(p_ + 512));                       \
    bf8 K2 = asbf8(*(const u16x8*)(p_ + 1024));                      \
    bf8 K3 = asbf8(*(const u16x8*)(p_ + 1536));                      \
    bf8 V0 = asbf8(*(const u16x8*)(p_ + 2048));                      \
    bf8 V1 = asbf8(*(const u16x8*)(p_ + 2560));                      \
    bf8 V2 = asbf8(*(const u16x8*)(p_ + 3072));                      \
    bf8 V3 = asbf8(*(const u16x8*)(p_ + 3584));                      \
    f32x16 s = {};                                                   \
    __builtin_amdgcn_s_setprio(1);                                   \
    s = MFMA32(K0, qf0, s);                                          \
    s = MFMA32(K1, qf1, s);                                          \
    s = MFMA32(K2, qf2, s);                                          \
    s = MFMA32(K3, qf3, s);                                          \
    __builtin_amdgcn_s_setprio(0);                                   \
    if ((bb) == kmax) {                                              \
      _Pragma("unroll") for (int r = 0; r < 16; ++r) {               \
        int kvr = (bb) * 32 + (r & 3) + 8 * (r >> 2) + 4 * hi;       \
        if (kvr > q0w + la) s[r] = -1e30f;                           \
      }                                                              \
    }                                                                \
    _Pragma("unroll") for (int r = 0; r < 16; ++r)                   \
      s[r] = ex2(s[r]);                                              \
    float z0 = s[0] + s[1],   z1 = s[2] + s[3];                      \
    float z2 = s[4] + s[5],   z3 = s[6] + s[7];                      \
    float z4 = s[8] + s[9],   z5 = s[10] + s[11];                    \
    float z6 = s[12] + s[13], z7 = s[14] + s[15];                    \
    l_run += ((z0 + z1) + (z2 + z3)) + ((z4 + z5) + (z6 + z7));      \
    u32 c0 = cvtpk(s[0], s[1]),   c1 = cvtpk(s[2], s[3]);            \
    u32 c2 = cvtpk(s[4], s[5]),   c3 = cvtpk(s[6], s[7]);            \
    u32 c4 = cvtpk(s[8], s[9]),   c5 = cvtpk(s[10], s[11]);          \
    u32 c6 = cvtpk(s[12], s[13]), c7 = cvtpk(s[14], s[15]);          \
    plswap(c0, c2); plswap(c1, c3); plswap(c4, c6); plswap(c5, c7);  \
    u32x4 t0; t0[0] = c0; t0[1] = c1; t0[2] = c2; t0[3] = c3;        \
    u32x4 t1; t1[0] = c4; t1[1] = c5; t1[2] = c6; t1[3] = c7;        \
    bf8 pa0 = __builtin_bit_cast(bf8, t0);                           \
    bf8 pa1 = __builtin_bit_cast(bf8, t1);                           \
    __builtin_amdgcn_s_setprio(1);                                   \
    o0 = MFMA32(pa0, V0, o0);                                        \
    o0 = MFMA32(pa1, V1, o0);                                        \
    o1 = MFMA32(pa0, V2, o1);                                        \
    o1 = MFMA32(pa1, V3, o1);                                        \
    __builtin_amdgcn_s_setprio(0);                                   \
  } while (0)

// wave stages its own (half, q-subtile) chunk: 4 x gll16 (K 2x512, V 2x512)
#define STG(bb, buf) do {                                            \
    u16* d_ = &smem[((h2 * 3 + (buf)) * 4096) + wq * 1024];          \
    const u16* kp_ = Kg + (size_t)(bb) * 2048 + wq * 1024 + lane8;   \
    const u16* vp_ = Vg + (size_t)(bb) * 2048 + wq * 1024 + lane8;   \
    gll16(kp_, d_);                                                  \
    gll16(kp_ + 512, d_ + 512);                                      \
    gll16(vp_, d_ + 2048);                                           \
    gll16(vp_ + 512, d_ + 2560);                                     \
  } while (0)

__global__ __launch_bounds__(256, 4) void attn_fwd(const u16* __restrict__ qkv,
                                                   const u16* __restrict__ Kf,
                                                   const u16* __restrict__ Vf,
                                                   u16* __restrict__ aout) {
  const int head = blockIdx.x;
  const int pid  = blockIdx.y;           // 0..15 (pair index)
  const int kh = head >> 2;              // GROUPS = 4
  const int t = threadIdx.x;
  const int w = t >> 6, lane = t & 63;
  const int h2 = w >> 1;                 // kv half
  const int wq = w & 1;                  // q sub-tile / staging sub
  const int la = lane & 31;
  const int hi = lane >> 5;
  const int lane8 = lane * 8;

  // staging: 6 slots (half x 3 bufs) x 4096 u16 = 48 KB
  // merge overlay: [4][32][72] u16 = 9216 u16, aliases slots (post-loop)
  __shared__ __align__(16) u16 smem[24576];
  __shared__ float lM[4][32];

  const u16* Kg = Kf + (size_t)kh * 131072;
  const u16* Vg = Vf + (size_t)kh * 131072;

#pragma unroll 1
  for (int pass = 0; pass < 2; ++pass) {
    const int qt = pass ? (31 - pid) : pid;
    const int Q0 = qt * 64;
    const int Kb = qt * 2;
    const int ha = Kb / 2 + 1;           // groups per half (= qt+1)
    const int q0w = Q0 + 32 * wq;
    const int kmax = Kb + wq;            // this wave's diagonal kv-group
    const int mybase = h2 ? ha : 0;

    // Q B-fragments, prescaled by 0.125*log2(e) (base-2 softmax domain)
    bf8 qf0, qf1, qf2, qf3;
    {
      const u16* qp = qkv + (size_t)(q0w + la) * 3072 + head * 64 + hi * 8;
      const float SC = 0.125f * 1.44269504088896340736f;
#define QLOAD(dst, kk) do {                                          \
        u16x8 v = *(const u16x8*)(qp + (kk) * 16);                   \
        u16x8 sv;                                                    \
        _Pragma("unroll") for (int e = 0; e < 8; ++e)                \
          sv[e] = f2b(b2f(v[e]) * SC);                               \
        dst = asbf8(sv);                                             \
      } while (0)
      QLOAD(qf0, 0); QLOAD(qf1, 1); QLOAD(qf2, 2); QLOAD(qf3, 3);
#undef QLOAD
    }

    f32x16 o0 = {}, o1 = {};
    float l_run = 0.f;

    STG(mybase, 0);                      // prologue: first tile into buf 0

    int buf = 0;
    for (int i = 0; i < ha; ++i) {
      const bool pf = (i + 1 < ha);
      const int nbuf = (buf == 2) ? 0 : buf + 1;
      if (pf) {
        STG(mybase + i + 1, nbuf);
        asm volatile("s_waitcnt vmcnt(4)" ::: "memory");
      } else {
        asm volatile("s_waitcnt vmcnt(0)" ::: "memory");
      }
      __builtin_amdgcn_s_barrier();      // all waves' cur-tile loads landed
      __builtin_amdgcn_sched_barrier(0);
      const int bb = mybase + i;
      if (bb <= kmax) STEPL(buf, bb);
      __builtin_amdgcn_sched_barrier(0);
      buf = nbuf;                        // NO trailing barrier (triple-buf)
    }
    __syncthreads();                     // all reads done before overlay

    // publish partials: l (half-combined) and O (bf16) into overlay
    {
      float lt = l_run + __shfl_xor(l_run, 32);
      if (lane < 32) lM[w][lane] = lt;
#pragma unroll
      for (int r = 0; r < 16; ++r) {
        int crow = (r & 3) + 8 * (r >> 2) + 4 * hi;
        smem[(w * 32 + crow) * 72 + la]      = f2b(o0[r]);
        smem[(w * 32 + crow) * 72 + la + 32] = f2b(o1[r]);
      }
    }
    __syncthreads();

    // merge: plain sums (shared static m). 512 items (64 q x 8 d-chunks)
#pragma unroll
    for (int it = 0; it < 2; ++it) {
      const int id = t + it * 256;
      const int q = id >> 3, d0 = (id & 7) * 8;
      const int wA = q >> 5, crow = q & 31;
      float inv = 1.0f / (lM[wA][crow] + lM[wA + 2][crow]);
      u16x8 a = *(const u16x8*)&smem[((wA)     * 32 + crow) * 72 + d0];
      u16x8 b = *(const u16x8*)&smem[((wA + 2) * 32 + crow) * 72 + d0];
      u16x8 outv;
#pragma unroll
      for (int j = 0; j < 8; ++j)
        outv[j] = f2b((b2f(a[j]) + b2f(b[j])) * inv);
      *(u16x8*)(aout + (size_t)(Q0 + q) * 2048 + head * 64 + d0) = outv;
    }
    __syncthreads();                     // before next pass reuses smem
  }
}

// ---------------- launch ----------------

extern "C" void kernel_launch(void* const* d_in, const int* in_sizes, int n_in,
                              void* d_out, int out_size, void* d_ws, size_t ws_size,
                              hipStream_t stream) {
  (void)in_sizes; (void)n_in; (void)out_size; (void)ws_size;
  const float* x  = (const float*)d_in[0];
  const float* wq = (const float*)d_in[1];
  const float* wk = (const float*)d_in[2];
  const float* wv = (const float*)d_in[3];
  const float* wo = (const float*)d_in[4];
  const float* cs = (const float*)d_in[5];
  const float* sn = (const float*)d_in[6];
  // d_in[7] = causal mask, implemented analytically

  u16* ws    = (u16*)d_ws;
  u16* xb    = ws;                         // [2048][2048] bf16 (later aout)
  u16* wqkvT = ws + 4194304;               // [3072][2048] bf16 (later Kf/Vf)
  u16* qkv   = ws + 10485760;              // [2048][3072] bf16; QKV partial z=0 in place
  u16* woT   = ws + 16777216;              // [2048][2048] bf16
  u16* ext   = ws + 20971520;              // [2048][3072] bf16: QKV partial z=1
  u16* Kf    = wqkvT;                      // [8][64][4][2][32][8] after QKV gemm
  u16* Vf    = wqkvT + 1048576;
  u16* aout  = xb;
  u16* op0   = qkv;                        // out-proj partials (qkv region free)
  u16* op1   = ext;

  prep_all<<<14336, 256, 0, stream>>>(x, wq, wk, wv, wo, xb, wqkvT, woT);

  // QKV: [2048][3072], split-K x2 (768 blocks), BK=64
  gemm_sk<<<dim3(24, 16, 2), 256, 0, stream>>>(xb, wqkvT, qkv, ext, 3072, 2048, 1024);
  reduce_qkv<<<3072, 256, 0, stream>>>(qkv, ext, Kf, Vf, cs, sn);
  attn_fwd<<<dim3(32, 16), 256, 0, stream>>>(qkv, Kf, Vf, aout);
  // out-proj: [2048][2048], split-K x2 (512 blocks), BK=64
  gemm_sk<<<dim3(16, 16, 2), 256, 0, stream>>>(aout, woT, op0, op1, 2048, 2048, 1024);
  reduce_out<<<2048, 256, 0, stream>>>(op0, op1, (float*)d_out);
}

// Round 17
// 129.785 us; speedup vs baseline: 1.0147x; 1.0147x over previous
//
#include <hip/hip_runtime.h>

typedef unsigned short u16;
typedef unsigned u32;
typedef u16 u16x8 __attribute__((ext_vector_type(8)));
typedef u16 u16x4 __attribute__((ext_vector_type(4)));
typedef u32 u32x4 __attribute__((ext_vector_type(4)));
typedef __bf16 bf8 __attribute__((ext_vector_type(8)));
typedef float f32x4 __attribute__((ext_vector_type(4)));
typedef float f32x16 __attribute__((ext_vector_type(16)));

__device__ __forceinline__ u16 f2b(float f) {
  unsigned u = __float_as_uint(f);
  u += 0x7FFFu + ((u >> 16) & 1u);   // RNE
  return (u16)(u >> 16);
}
__device__ __forceinline__ float b2f(u16 h) {
  return __uint_as_float(((unsigned)h) << 16);
}
__device__ __forceinline__ bf8 asbf8(u16x8 v) {
  return __builtin_bit_cast(bf8, v);
}
__device__ __forceinline__ void gll16(const u16* g, u16* l) {
  __builtin_amdgcn_global_load_lds(
      (const __attribute__((address_space(1))) unsigned*)(g),
      (__attribute__((address_space(3))) unsigned*)(l), 16, 0, 0);
}
__device__ __forceinline__ u32 cvtpk(float lo, float hi) {
  u32 r;
  asm("v_cvt_pk_bf16_f32 %0, %1, %2" : "=v"(r) : "v"(lo), "v"(hi));
  return r;
}
// v_permlane32_swap_b32 a, b:  a.hi32lanes <-> b.lo32lanes
__device__ __forceinline__ void plswap(u32& a, u32& b) {
  asm("v_permlane32_swap_b32 %0, %1" : "+v"(a), "+v"(b));
}
__device__ __forceinline__ float ex2(float x) {
  return __builtin_amdgcn_exp2f(x);
}
#define MFMA32(A,B,C) __builtin_amdgcn_mfma_f32_32x32x16_bf16(A,B,C,0,0,0)

// ---------------- fused prep: xconv + 4x wtrans in one dispatch ----------

__global__ __launch_bounds__(256) void prep_all(const float* __restrict__ x,
                                                const float* __restrict__ wqp,
                                                const float* __restrict__ wkp,
                                                const float* __restrict__ wvp,
                                                const float* __restrict__ wop,
                                                u16* __restrict__ xb,
                                                u16* __restrict__ wqkvT,
                                                u16* __restrict__ woT) {
  const int bid = blockIdx.x;
  if (bid < 4096) {                    // xconv
    int i = (bid * 256 + threadIdx.x) * 4;
    float4 v = *(const float4*)(x + i);
    u16x4 o;
    o[0] = f2b(v.x); o[1] = f2b(v.y); o[2] = f2b(v.z); o[3] = f2b(v.w);
    *(u16x4*)(xb + i) = o;
    return;
  }
  __shared__ float tile[32][33];
  const float* in; u16* out; int N, bx, by;
  if (bid < 8192)       { int b = bid - 4096;  in = wqp; out = wqkvT;                         N = 2048; bx = b & 63; by = b >> 6; }
  else if (bid < 9216)  { int b = bid - 8192;  in = wkp; out = wqkvT + (size_t)2048 * 2048;   N = 512;  bx = b & 15; by = b >> 4; }
  else if (bid < 10240) { int b = bid - 9216;  in = wvp; out = wqkvT + (size_t)2560 * 2048;   N = 512;  bx = b & 15; by = b >> 4; }
  else                  { int b = bid - 10240; in = wop; out = woT;                           N = 2048; bx = b & 63; by = b >> 6; }
  const int K = 2048;
  int tx = threadIdx.x & 31, ty = threadIdx.x >> 5;
  int n0 = bx * 32, k0 = by * 32;
#pragma unroll
  for (int yy = 0; yy < 32; yy += 8)
    tile[ty + yy][tx] = in[(size_t)(k0 + ty + yy) * N + n0 + tx];
  __syncthreads();
#pragma unroll
  for (int yy = 0; yy < 32; yy += 8)
    out[(size_t)(n0 + ty + yy) * K + k0 + tx] = f2b(tile[tx][ty + yy]);
}

// split-K reduce + RoPE + fused KV fragment repack.
__global__ __launch_bounds__(256) void reduce_qkv(u16* __restrict__ p0,
                                                  const u16* __restrict__ p1,
                                                  u16* __restrict__ Kf,
                                                  u16* __restrict__ Vf,
                                                  const float* __restrict__ cs,
                                                  const float* __restrict__ sn) {
  int idx = blockIdx.x * 256 + threadIdx.x;      // 2048*384
  int s = idx / 384, c8 = (idx % 384) * 8;
  size_t base = (size_t)s * 3072 + c8;
  if (c8 < 2560) {                               // q or k head: RoPE pairs
    int hc = c8 & 63;
    if (hc >= 32) return;                        // partner handles
    u16x8 a0 = *(const u16x8*)(p0 + base);
    u16x8 a1 = *(const u16x8*)(p1 + base);
    u16x8 b0 = *(const u16x8*)(p0 + base + 32);
    u16x8 b1 = *(const u16x8*)(p1 + base + 32);
    u16x8 oa, ob;
#pragma unroll
    for (int e = 0; e < 8; ++e) {
      float va = b2f(a0[e]) + b2f(a1[e]);
      float vb = b2f(b0[e]) + b2f(b1[e]);
      float c1 = cs[s * 64 + hc + e],      s1 = sn[s * 64 + hc + e];
      float c2 = cs[s * 64 + hc + 32 + e], s2 = sn[s * 64 + hc + 32 + e];
      oa[e] = f2b(va * c1 - vb * s1);
      ob[e] = f2b(vb * c2 + va * s2);
    }
    if (c8 < 2048) {                             // Q: back to qkv
      *(u16x8*)(p0 + base)      = oa;
      *(u16x8*)(p0 + base + 32) = ob;
    } else {                                     // K: to fragment-major Kf
      int kh = (c8 - 2048) >> 6;
      int d0 = hc;                               // < 32, multiple of 8
      int b = s >> 5, la = s & 31;
      int j0 = d0 >> 4, hi0 = (d0 >> 3) & 1;
      size_t f0 = ((((size_t)(kh * 64 + b) * 4 + j0) * 2 + hi0) * 32 + la) * 8;
      size_t f1 = ((((size_t)(kh * 64 + b) * 4 + j0 + 2) * 2 + hi0) * 32 + la) * 8;
      *(u16x8*)(Kf + f0) = oa;
      *(u16x8*)(Kf + f1) = ob;
    }
  } else {                                       // V: sum -> Vf fragments
    u16x8 a0 = *(const u16x8*)(p0 + base);
    u16x8 a1 = *(const u16x8*)(p1 + base);
    int c = c8 - 2560;
    int kh = c >> 6, d0 = c & 63;
    int m = d0 >> 5, la0 = d0 & 31;
    int b = s >> 5, s5 = s & 31;
    int jj = s5 >> 4, hi = (s5 >> 3) & 1, e = s5 & 7;
    u16* dst = Vf + (((size_t)(kh * 64 + b) * 4 + m * 2 + jj) * 64 + hi * 32 + la0) * 8 + e;
#pragma unroll
    for (int i = 0; i < 8; ++i)
      dst[i * 8] = f2b(b2f(a0[i]) + b2f(a1[i]));
  }
}

// split-K reduce for out-proj -> f32 d_out
__global__ __launch_bounds__(256) void reduce_out(const u16* __restrict__ p0,
                                                  const u16* __restrict__ p1,
                                                  float* __restrict__ out) {
  int idx = blockIdx.x * 256 + threadIdx.x;      // 2048*256
  size_t base = (size_t)idx * 8;
  u16x8 a0 = *(const u16x8*)(p0 + base);
  u16x8 a1 = *(const u16x8*)(p1 + base);
  float4 lo, hi;
  lo.x = b2f(a0[0]) + b2f(a1[0]); lo.y = b2f(a0[1]) + b2f(a1[1]);
  lo.z = b2f(a0[2]) + b2f(a1[2]); lo.w = b2f(a0[3]) + b2f(a1[3]);
  hi.x = b2f(a0[4]) + b2f(a1[4]); hi.y = b2f(a0[5]) + b2f(a1[5]);
  hi.z = b2f(a0[6]) + b2f(a1[6]); hi.w = b2f(a0[7]) + b2f(a1[7]);
  *(float4*)(out + base)     = lo;
  *(float4*)(out + base + 4) = hi;
}

// ------- split-K GEMM, BK=64, XOR-swizzled LDS ----------------------------

__global__ __launch_bounds__(256) void gemm_sk(const u16* __restrict__ A,
                                               const u16* __restrict__ Bt,
                                               u16* __restrict__ C0,
                                               u16* __restrict__ C1,
                                               int N, int Kfull, int KH) {
  __shared__ __align__(16) u16 As[128 * 64];
  __shared__ __align__(16) u16 Bs[128 * 64];
  const int t = threadIdx.x;
  const int lane = t & 63, wid = t >> 6;
  const int wm = (wid >> 1) * 64, wn = (wid & 1) * 64;
  const int la = lane & 15, lg = lane >> 4;
  const int m0 = blockIdx.y * 128, n0 = blockIdx.x * 128;
  const int kbeg = blockIdx.z * KH;
  u16* C = blockIdx.z ? C1 : C0;

  const int srow0 = wid * 32 + (lane >> 3);
  const int scolsw = (((lane & 7) ^ (lane >> 3))) * 8;   // pre-swizzled col
  const u16* Ap = A + (size_t)(m0 + srow0) * Kfull + kbeg + scolsw;
  const u16* Bp = Bt + (size_t)(n0 + srow0) * Kfull + kbeg + scolsw;
  u16* Adst = &As[wid * 2048];
  u16* Bdst = &Bs[wid * 2048];
  const size_t rstep8 = (size_t)8 * Kfull;

  f32x4 acc[4][4] = {};

  for (int k0 = 0; k0 < KH; k0 += 64) {
    __syncthreads();
#pragma unroll
    for (int cc = 0; cc < 4; ++cc)
      gll16(Ap + k0 + cc * rstep8, Adst + cc * 512);
#pragma unroll
    for (int cc = 0; cc < 4; ++cc)
      gll16(Bp + k0 + cc * rstep8, Bdst + cc * 512);
    __syncthreads();
#pragma unroll
    for (int kk = 0; kk < 2; ++kk) {
      bf8 af[4], bfr[4];
#pragma unroll
      for (int i = 0; i < 4; ++i) {
        const int row = wm + i * 16 + la;
        const int c8 = (kk * 4 + lg) ^ (row & 7);
        af[i] = asbf8(*(const u16x8*)(&As[row * 64 + c8 * 8]));
      }
#pragma unroll
      for (int j = 0; j < 4; ++j) {
        const int row = wn + j * 16 + la;
        const int c8 = (kk * 4 + lg) ^ (row & 7);
        bfr[j] = asbf8(*(const u16x8*)(&Bs[row * 64 + c8 * 8]));
      }
      __builtin_amdgcn_s_setprio(1);
#pragma unroll
      for (int i = 0; i < 4; ++i)
#pragma unroll
        for (int j = 0; j < 4; ++j)
          acc[i][j] = __builtin_amdgcn_mfma_f32_16x16x32_bf16(af[i], bfr[j],
                                                              acc[i][j], 0, 0, 0);
      __builtin_amdgcn_s_setprio(0);
    }
  }

#pragma unroll
  for (int i = 0; i < 4; ++i)
#pragma unroll
    for (int j = 0; j < 4; ++j)
#pragma unroll
      for (int r = 0; r < 4; ++r) {
        int row = m0 + wm + i * 16 + lg * 4 + r;
        int col = n0 + wn + j * 16 + la;
        C[(size_t)row * N + col] = f2b(acc[i][j][r]);
      }
}

// --- flash attention: ZERO-BARRIER wave-private LDS pipeline --------------
// Block = (head, 64 q rows), 4 waves = 2 q-subtiles x 2 kv-halves. Each wave
// owns a private 8KB LDS slot (single buffer) and its own kv-groups: per iter
// vmcnt(0) -> ds_read 8 frags -> lgkmcnt(0) -> issue NEXT group's 8 gll16 ->
// compute (~600cy hides L2 latency). No cross-wave barrier until the merge:
// 16 independent waves/CU. Static-max softmax (P = 2^s); 2-half LDS-sum merge.

#define STG(bb) do {                                                 \
    u16* d_ = &smem[w * 4096];                                       \
    const u16* kp_ = Kg + (size_t)(bb) * 2048 + lane8;               \
    const u16* vp_ = Vg + (size_t)(bb) * 2048 + lane8;               \
    gll16(kp_, d_);                                                  \
    gll16(kp_ + 512, d_ + 512);                                      \
    gll16(kp_ + 1024, d_ + 1024);                                    \
    gll16(kp_ + 1536, d_ + 1536);                                    \
    gll16(vp_, d_ + 2048);                                           \
    gll16(vp_ + 512, d_ + 2560);                                     \
    gll16(vp_ + 1024, d_ + 3072);                                    \
    gll16(vp_ + 1536, d_ + 3584);                                    \
  } while (0)

__global__ __launch_bounds__(256, 4) void attn_fwd(const u16* __restrict__ qkv,
                                                   const u16* __restrict__ Kf,
                                                   const u16* __restrict__ Vf,
                                                   u16* __restrict__ aout) {
  const int head = blockIdx.x;
  const int qt = 31 - (int)blockIdx.y;   // heavy q-blocks dispatch first
  const int Q0 = qt * 64;
  const int Kb = qt * 2;
  const int ha = Kb / 2 + 1;             // groups per half (= qt+1)
  const int kh = head >> 2;              // GROUPS = 4
  const int t = threadIdx.x;
  const int w = t >> 6, lane = t & 63;
  const int h2 = w >> 1;                 // kv half
  const int wq = w & 1;                  // q sub-tile
  const int la = lane & 31;
  const int hi = lane >> 5;
  const int lane8 = lane * 8;
  const int q0w = Q0 + 32 * wq;
  const int kmax = Kb + wq;              // this wave's diagonal kv-group
  const int mybase = h2 ? ha : 0;
  const int myn = min(ha, kmax - mybase + 1);   // groups this wave computes

  // wave-private staging: 4 slots x 4096 u16 (K 2048 | V 2048) = 32 KB
  // merge overlay: [4][32][72] u16 = 9216 u16, aliased post-loop
  __shared__ __align__(16) u16 smem[16384];
  __shared__ float lM[4][32];

  // Q B-fragments, prescaled by 0.125*log2(e) (base-2 softmax domain)
  bf8 qf0, qf1, qf2, qf3;
  {
    const u16* qp = qkv + (size_t)(q0w + la) * 3072 + head * 64 + hi * 8;
    const float SC = 0.125f * 1.44269504088896340736f;
#define QLOAD(dst, kk) do {                                          \
      u16x8 v = *(const u16x8*)(qp + (kk) * 16);                     \
      u16x8 sv;                                                      \
      _Pragma("unroll") for (int e = 0; e < 8; ++e)                  \
        sv[e] = f2b(b2f(v[e]) * SC);                                 \
      dst = asbf8(sv);                                               \
    } while (0)
    QLOAD(qf0, 0); QLOAD(qf1, 1); QLOAD(qf2, 2); QLOAD(qf3, 3);
#undef QLOAD
  }

  const u16* Kg = Kf + (size_t)kh * 131072;
  const u16* Vg = Vf + (size_t)kh * 131072;

  f32x16 o0 = {}, o1 = {};
  float l_run = 0.f;

  if (myn > 0) STG(mybase);              // prologue: first group

  for (int i = 0; i < myn; ++i) {
    asm volatile("s_waitcnt vmcnt(0)" ::: "memory");   // group i landed
    __builtin_amdgcn_sched_barrier(0);
    const int bb = mybase + i;
    const u16* p_ = &smem[w * 4096 + lane8];
    bf8 K0 = asbf8(*(const u16x8*)(p_));
    bf8 K1 = asbf8(*(const u16x8*)(p_ + 512));
    bf8 K2 = asbf8(*(const u16x8*)(p_ + 1024));
    bf8 K3 = asbf8(*(const u16x8*)(p_ + 1536));
    bf8 V0 = asbf8(*(const u16x8*)(p_ + 2048));
    bf8 V1 = asbf8(*(const u16x8*)(p_ + 2560));
    bf8 V2 = asbf8(*(const u16x8*)(p_ + 3072));
    bf8 V3 = asbf8(*(const u16x8*)(p_ + 3584));
    asm volatile("s_waitcnt lgkmcnt(0)" ::: "memory"); // reads retired
    __builtin_amdgcn_sched_barrier(0);
    if (i + 1 < myn) STG(bb + 1);        // overwrite is now WAR-safe;
                                         // L2 latency hides under compute
    f32x16 s = {};
    __builtin_amdgcn_s_setprio(1);
    s = MFMA32(K0, qf0, s);
    s = MFMA32(K1, qf1, s);
    s = MFMA32(K2, qf2, s);
    s = MFMA32(K3, qf3, s);
    __builtin_amdgcn_s_setprio(0);
    if (bb == kmax) {                    // diagonal group: causal mask
#pragma unroll
      for (int r = 0; r < 16; ++r) {
        int kvr = bb * 32 + (r & 3) + 8 * (r >> 2) + 4 * hi;
        if (kvr > q0w + la) s[r] = -1e30f;
      }
    }
#pragma unroll
    for (int r = 0; r < 16; ++r) s[r] = ex2(s[r]);
    {
      float z0 = s[0] + s[1],   z1 = s[2] + s[3];
      float z2 = s[4] + s[5],   z3 = s[6] + s[7];
      float z4 = s[8] + s[9],   z5 = s[10] + s[11];
      float z6 = s[12] + s[13], z7 = s[14] + s[15];
      l_run += ((z0 + z1) + (z2 + z3)) + ((z4 + z5) + (z6 + z7));
    }
    u32 c0 = cvtpk(s[0], s[1]),   c1 = cvtpk(s[2], s[3]);
    u32 c2 = cvtpk(s[4], s[5]),   c3 = cvtpk(s[6], s[7]);
    u32 c4 = cvtpk(s[8], s[9]),   c5 = cvtpk(s[10], s[11]);
    u32 c6 = cvtpk(s[12], s[13]), c7 = cvtpk(s[14], s[15]);
    plswap(c0, c2); plswap(c1, c3); plswap(c4, c6); plswap(c5, c7);
    u32x4 t0; t0[0] = c0; t0[1] = c1; t0[2] = c2; t0[3] = c3;
    u32x4 t1; t1[0] = c4; t1[1] = c5; t1[2] = c6; t1[3] = c7;
    bf8 pa0 = __builtin_bit_cast(bf8, t0);
    bf8 pa1 = __builtin_bit_cast(bf8, t1);
    __builtin_amdgcn_s_setprio(1);
    o0 = MFMA32(pa0, V0, o0);
    o0 = MFMA32(pa1, V1, o0);
    o1 = MFMA32(pa0, V2, o1);
    o1 = MFMA32(pa1, V3, o1);
    __builtin_amdgcn_s_setprio(0);
  }

  __syncthreads();                       // all waves done with private slots

  // publish partials: l (half-combined) and O (bf16) into overlay
  {
    float lt = l_run + __shfl_xor(l_run, 32);
    if (lane < 32) lM[w][lane] = lt;
#pragma unroll
    for (int r = 0; r < 16; ++r) {
      int crow = (r & 3) + 8 * (r >> 2) + 4 * hi;
      smem[(w * 32 + crow) * 72 + la]      = f2b(o0[r]);
      smem[(w * 32 + crow) * 72 + la + 32] = f2b(o1[r]);
    }
  }
  __syncthreads();

  // merge: plain sums (shared static m). 512 items (64 q x 8 d-chunks)
#pragma unroll
  for (int it = 0; it < 2; ++it) {
    const int id = t + it * 256;
    const int q = id >> 3, d0 = (id & 7) * 8;
    const int wA = q >> 5, crow = q & 31;
    float inv = 1.0f / (lM[wA][crow] + lM[wA + 2][crow]);
    u16x8 a = *(const u16x8*)&smem[((wA)     * 32 + crow) * 72 + d0];
    u16x8 b = *(const u16x8*)&smem[((wA + 2) * 32 + crow) * 72 + d0];
    u16x8 outv;
#pragma unroll
    for (int j = 0; j < 8; ++j)
      outv[j] = f2b((b2f(a[j]) + b2f(b[j])) * inv);
    *(u16x8*)(aout + (size_t)(Q0 + q) * 2048 + head * 64 + d0) = outv;
  }
}

// ---------------- launch ----------------

extern "C" void kernel_launch(void* const* d_in, const int* in_sizes, int n_in,
                              void* d_out, int out_size, void* d_ws, size_t ws_size,
                              hipStream_t stream) {
  (void)in_sizes; (void)n_in; (void)out_size; (void)ws_size;
  const float* x  = (const float*)d_in[0];
  const float* wq = (const float*)d_in[1];
  const float* wk = (const float*)d_in[2];
  const float* wv = (const float*)d_in[3];
  const float* wo = (const float*)d_in[4];
  const float* cs = (const float*)d_in[5];
  const float* sn = (const float*)d_in[6];
  // d_in[7] = causal mask, implemented analytically

  u16* ws    = (u16*)d_ws;
  u16* xb    = ws;                         // [2048][2048] bf16 (later aout)
  u16* wqkvT = ws + 4194304;               // [3072][2048] bf16 (later Kf/Vf)
  u16* qkv   = ws + 10485760;              // [2048][3072] bf16; QKV partial z=0 in place
  u16* woT   = ws + 16777216;              // [2048][2048] bf16
  u16* ext   = ws + 20971520;              // [2048][3072] bf16: QKV partial z=1
  u16* Kf    = wqkvT;                      // [8][64][4][2][32][8] after QKV gemm
  u16* Vf    = wqkvT + 1048576;
  u16* aout  = xb;
  u16* op0   = qkv;                        // out-proj partials (qkv region free)
  u16* op1   = ext;

  prep_all<<<14336, 256, 0, stream>>>(x, wq, wk, wv, wo, xb, wqkvT, woT);

  // QKV: [2048][3072], split-K x2 (768 blocks), BK=64
  gemm_sk<<<dim3(24, 16, 2), 256, 0, stream>>>(xb, wqkvT, qkv, ext, 3072, 2048, 1024);
  reduce_qkv<<<3072, 256, 0, stream>>>(qkv, ext, Kf, Vf, cs, sn);
  attn_fwd<<<dim3(32, 32), 256, 0, stream>>>(qkv, Kf, Vf, aout);
  // out-proj: [2048][2048], split-K x2 (512 blocks), BK=64
  gemm_sk<<<dim3(16, 16, 2), 256, 0, stream>>>(aout, woT, op0, op1, 2048, 2048, 1024);
  reduce_out<<<2048, 256, 0, stream>>>(op0, op1, (float*)d_out);
}

// Round 18
// 128.869 us; speedup vs baseline: 1.0219x; 1.0071x over previous
//
#include <hip/hip_runtime.h>

typedef unsigned short u16;
typedef unsigned u32;
typedef u16 u16x8 __attribute__((ext_vector_type(8)));
typedef u16 u16x4 __attribute__((ext_vector_type(4)));
typedef u32 u32x4 __attribute__((ext_vector_type(4)));
typedef __bf16 bf8 __attribute__((ext_vector_type(8)));
typedef float f32x4 __attribute__((ext_vector_type(4)));
typedef float f32x16 __attribute__((ext_vector_type(16)));

__device__ __forceinline__ u16 f2b(float f) {
  unsigned u = __float_as_uint(f);
  u += 0x7FFFu + ((u >> 16) & 1u);   // RNE
  return (u16)(u >> 16);
}
__device__ __forceinline__ float b2f(u16 h) {
  return __uint_as_float(((unsigned)h) << 16);
}
__device__ __forceinline__ bf8 asbf8(u16x8 v) {
  return __builtin_bit_cast(bf8, v);
}
__device__ __forceinline__ void gll16(const u16* g, u16* l) {
  __builtin_amdgcn_global_load_lds(
      (const __attribute__((address_space(1))) unsigned*)(g),
      (__attribute__((address_space(3))) unsigned*)(l), 16, 0, 0);
}
__device__ __forceinline__ u32 cvtpk(float lo, float hi) {
  u32 r;
  asm("v_cvt_pk_bf16_f32 %0, %1, %2" : "=v"(r) : "v"(lo), "v"(hi));
  return r;
}
// v_permlane32_swap_b32 a, b:  a.hi32lanes <-> b.lo32lanes
__device__ __forceinline__ void plswap(u32& a, u32& b) {
  asm("v_permlane32_swap_b32 %0, %1" : "+v"(a), "+v"(b));
}
__device__ __forceinline__ float ex2(float x) {
  return __builtin_amdgcn_exp2f(x);
}
#define MFMA32(A,B,C) __builtin_amdgcn_mfma_f32_32x32x16_bf16(A,B,C,0,0,0)

// -------- fused prep: xconv + 4x wtrans (64x64 float4 tiles) -------------

__global__ __launch_bounds__(256) void prep_all(const float* __restrict__ x,
                                                const float* __restrict__ wqp,
                                                const float* __restrict__ wkp,
                                                const float* __restrict__ wvp,
                                                const float* __restrict__ wop,
                                                u16* __restrict__ xb,
                                                u16* __restrict__ wqkvT,
                                                u16* __restrict__ woT) {
  const int bid = blockIdx.x;
  if (bid < 4096) {                    // xconv
    int i = (bid * 256 + threadIdx.x) * 4;
    float4 v = *(const float4*)(x + i);
    u16x4 o;
    o[0] = f2b(v.x); o[1] = f2b(v.y); o[2] = f2b(v.z); o[3] = f2b(v.w);
    *(u16x4*)(xb + i) = o;
    return;
  }
  // wtrans 64x64: in [K=2048][N] f32 -> out [N][2048] bf16
  __shared__ float tile[64][65];
  const float* in; u16* out; int N, bx, by;
  int b = bid - 4096;
  if (b < 1024)      { in = wqp; out = wqkvT;                       N = 2048; bx = b & 31;          by = b >> 5; }
  else if (b < 1280) { in = wkp; out = wqkvT + (size_t)2048 * 2048; N = 512;  bx = (b - 1024) & 7;  by = (b - 1024) >> 3; }
  else if (b < 1536) { in = wvp; out = wqkvT + (size_t)2560 * 2048; N = 512;  bx = (b - 1280) & 7;  by = (b - 1280) >> 3; }
  else               { in = wop; out = woT;                         N = 2048; bx = (b - 1536) & 31; by = (b - 1536) >> 5; }
  const int K = 2048;
  const int tx = threadIdx.x & 15, ty = threadIdx.x >> 4;
  const int n0 = bx * 64, k0 = by * 64;
#pragma unroll
  for (int i = 0; i < 4; ++i) {
    float4 v = *(const float4*)(in + (size_t)(k0 + ty + 16 * i) * N + n0 + tx * 4);
    tile[ty + 16 * i][tx * 4 + 0] = v.x;
    tile[ty + 16 * i][tx * 4 + 1] = v.y;
    tile[ty + 16 * i][tx * 4 + 2] = v.z;
    tile[ty + 16 * i][tx * 4 + 3] = v.w;
  }
  __syncthreads();
#pragma unroll
  for (int i = 0; i < 4; ++i) {
    const int r = ty + 16 * i;         // output n-row
    u16x4 o;
#pragma unroll
    for (int j = 0; j < 4; ++j) o[j] = f2b(tile[tx * 4 + j][r]);
    *(u16x4*)(out + (size_t)(n0 + r) * K + k0 + tx * 4) = o;
  }
}

// split-K reduce + RoPE + fused KV fragment repack.
__global__ __launch_bounds__(256) void reduce_qkv(u16* __restrict__ p0,
                                                  const u16* __restrict__ p1,
                                                  u16* __restrict__ Kf,
                                                  u16* __restrict__ Vf,
                                                  const float* __restrict__ cs,
                                                  const float* __restrict__ sn) {
  int idx = blockIdx.x * 256 + threadIdx.x;      // 2048*384
  int s = idx / 384, c8 = (idx % 384) * 8;
  size_t base = (size_t)s * 3072 + c8;
  if (c8 < 2560) {                               // q or k head: RoPE pairs
    int hc = c8 & 63;
    if (hc >= 32) return;                        // partner handles
    u16x8 a0 = *(const u16x8*)(p0 + base);
    u16x8 a1 = *(const u16x8*)(p1 + base);
    u16x8 b0 = *(const u16x8*)(p0 + base + 32);
    u16x8 b1 = *(const u16x8*)(p1 + base + 32);
    u16x8 oa, ob;
#pragma unroll
    for (int e = 0; e < 8; ++e) {
      float va = b2f(a0[e]) + b2f(a1[e]);
      float vb = b2f(b0[e]) + b2f(b1[e]);
      float c1 = cs[s * 64 + hc + e],      s1 = sn[s * 64 + hc + e];
      float c2 = cs[s * 64 + hc + 32 + e], s2 = sn[s * 64 + hc + 32 + e];
      oa[e] = f2b(va * c1 - vb * s1);
      ob[e] = f2b(vb * c2 + va * s2);
    }
    if (c8 < 2048) {                             // Q: back to qkv
      *(u16x8*)(p0 + base)      = oa;
      *(u16x8*)(p0 + base + 32) = ob;
    } else {                                     // K: to fragment-major Kf
      int kh = (c8 - 2048) >> 6;
      int d0 = hc;                               // < 32, multiple of 8
      int b = s >> 5, la = s & 31;
      int j0 = d0 >> 4, hi0 = (d0 >> 3) & 1;
      size_t f0 = ((((size_t)(kh * 64 + b) * 4 + j0) * 2 + hi0) * 32 + la) * 8;
      size_t f1 = ((((size_t)(kh * 64 + b) * 4 + j0 + 2) * 2 + hi0) * 32 + la) * 8;
      *(u16x8*)(Kf + f0) = oa;
      *(u16x8*)(Kf + f1) = ob;
    }
  } else {                                       // V: sum -> Vf fragments
    u16x8 a0 = *(const u16x8*)(p0 + base);
    u16x8 a1 = *(const u16x8*)(p1 + base);
    int c = c8 - 2560;
    int kh = c >> 6, d0 = c & 63;
    int m = d0 >> 5, la0 = d0 & 31;
    int b = s >> 5, s5 = s & 31;
    int jj = s5 >> 4, hi = (s5 >> 3) & 1, e = s5 & 7;
    u16* dst = Vf + (((size_t)(kh * 64 + b) * 4 + m * 2 + jj) * 64 + hi * 32 + la0) * 8 + e;
#pragma unroll
    for (int i = 0; i < 8; ++i)
      dst[i * 8] = f2b(b2f(a0[i]) + b2f(a1[i]));
  }
}

// 3-way split-K reduce for out-proj -> f32 d_out
__global__ __launch_bounds__(256) void reduce_out3(const u16* __restrict__ p0,
                                                   const u16* __restrict__ p1,
                                                   const u16* __restrict__ p2,
                                                   float* __restrict__ out) {
  int idx = blockIdx.x * 256 + threadIdx.x;      // 2048*256
  size_t base = (size_t)idx * 8;
  u16x8 a0 = *(const u16x8*)(p0 + base);
  u16x8 a1 = *(const u16x8*)(p1 + base);
  u16x8 a2 = *(const u16x8*)(p2 + base);
  float4 lo, hi;
  lo.x = b2f(a0[0]) + b2f(a1[0]) + b2f(a2[0]);
  lo.y = b2f(a0[1]) + b2f(a1[1]) + b2f(a2[1]);
  lo.z = b2f(a0[2]) + b2f(a1[2]) + b2f(a2[2]);
  lo.w = b2f(a0[3]) + b2f(a1[3]) + b2f(a2[3]);
  hi.x = b2f(a0[4]) + b2f(a1[4]) + b2f(a2[4]);
  hi.y = b2f(a0[5]) + b2f(a1[5]) + b2f(a2[5]);
  hi.z = b2f(a0[6]) + b2f(a1[6]) + b2f(a2[6]);
  hi.w = b2f(a0[7]) + b2f(a1[7]) + b2f(a2[7]);
  *(float4*)(out + base)     = lo;
  *(float4*)(out + base + 4) = hi;
}

// ------- split-K GEMM, BK=64, XOR-swizzled LDS; z picks K-slice ----------
// kbeg = z*KH; local K-extent = min(KH, Kfull-kbeg) (multiple of 64).

__global__ __launch_bounds__(256) void gemm_sk(const u16* __restrict__ A,
                                               const u16* __restrict__ Bt,
                                               u16* __restrict__ C0,
                                               u16* __restrict__ C1,
                                               u16* __restrict__ C2,
                                               int N, int Kfull, int KH) {
  __shared__ __align__(16) u16 As[128 * 64];
  __shared__ __align__(16) u16 Bs[128 * 64];
  const int t = threadIdx.x;
  const int lane = t & 63, wid = t >> 6;
  const int wm = (wid >> 1) * 64, wn = (wid & 1) * 64;
  const int la = lane & 15, lg = lane >> 4;
  const int m0 = blockIdx.y * 128, n0 = blockIdx.x * 128;
  const int kbeg = blockIdx.z * KH;
  const int KHloc = min(KH, Kfull - kbeg);
  u16* C = (blockIdx.z == 0) ? C0 : (blockIdx.z == 1 ? C1 : C2);

  const int srow0 = wid * 32 + (lane >> 3);
  const int scolsw = (((lane & 7) ^ (lane >> 3))) * 8;   // pre-swizzled col
  const u16* Ap = A + (size_t)(m0 + srow0) * Kfull + kbeg + scolsw;
  const u16* Bp = Bt + (size_t)(n0 + srow0) * Kfull + kbeg + scolsw;
  u16* Adst = &As[wid * 2048];
  u16* Bdst = &Bs[wid * 2048];
  const size_t rstep8 = (size_t)8 * Kfull;

  f32x4 acc[4][4] = {};

  for (int k0 = 0; k0 < KHloc; k0 += 64) {
    __syncthreads();
#pragma unroll
    for (int cc = 0; cc < 4; ++cc)
      gll16(Ap + k0 + cc * rstep8, Adst + cc * 512);
#pragma unroll
    for (int cc = 0; cc < 4; ++cc)
      gll16(Bp + k0 + cc * rstep8, Bdst + cc * 512);
    __syncthreads();
#pragma unroll
    for (int kk = 0; kk < 2; ++kk) {
      bf8 af[4], bfr[4];
#pragma unroll
      for (int i = 0; i < 4; ++i) {
        const int row = wm + i * 16 + la;
        const int c8 = (kk * 4 + lg) ^ (row & 7);
        af[i] = asbf8(*(const u16x8*)(&As[row * 64 + c8 * 8]));
      }
#pragma unroll
      for (int j = 0; j < 4; ++j) {
        const int row = wn + j * 16 + la;
        const int c8 = (kk * 4 + lg) ^ (row & 7);
        bfr[j] = asbf8(*(const u16x8*)(&Bs[row * 64 + c8 * 8]));
      }
      __builtin_amdgcn_s_setprio(1);
#pragma unroll
      for (int i = 0; i < 4; ++i)
#pragma unroll
        for (int j = 0; j < 4; ++j)
          acc[i][j] = __builtin_amdgcn_mfma_f32_16x16x32_bf16(af[i], bfr[j],
                                                              acc[i][j], 0, 0, 0);
      __builtin_amdgcn_s_setprio(0);
    }
  }

#pragma unroll
  for (int i = 0; i < 4; ++i)
#pragma unroll
    for (int j = 0; j < 4; ++j)
#pragma unroll
      for (int r = 0; r < 4; ++r) {
        int row = m0 + wm + i * 16 + lg * 4 + r;
        int col = n0 + wn + j * 16 + la;
        C[(size_t)row * N + col] = f2b(acc[i][j][r]);
      }
}

// --- flash attention: ZERO-BARRIER wave-private LDS pipeline (frozen) -----

#define STG(bb) do {                                                 \
    u16* d_ = &smem[w * 4096];                                       \
    const u16* kp_ = Kg + (size_t)(bb) * 2048 + lane8;               \
    const u16* vp_ = Vg + (size_t)(bb) * 2048 + lane8;               \
    gll16(kp_, d_);                                                  \
    gll16(kp_ + 512, d_ + 512);                                      \
    gll16(kp_ + 1024, d_ + 1024);                                    \
    gll16(kp_ + 1536, d_ + 1536);                                    \
    gll16(vp_, d_ + 2048);                                           \
    gll16(vp_ + 512, d_ + 2560);                                     \
    gll16(vp_ + 1024, d_ + 3072);                                    \
    gll16(vp_ + 1536, d_ + 3584);                                    \
  } while (0)

__global__ __launch_bounds__(256, 4) void attn_fwd(const u16* __restrict__ qkv,
                                                   const u16* __restrict__ Kf,
                                                   const u16* __restrict__ Vf,
                                                   u16* __restrict__ aout) {
  const int head = blockIdx.x;
  const int qt = 31 - (int)blockIdx.y;   // heavy q-blocks dispatch first
  const int Q0 = qt * 64;
  const int Kb = qt * 2;
  const int ha = Kb / 2 + 1;             // groups per half (= qt+1)
  const int kh = head >> 2;              // GROUPS = 4
  const int t = threadIdx.x;
  const int w = t >> 6, lane = t & 63;
  const int h2 = w >> 1;                 // kv half
  const int wq = w & 1;                  // q sub-tile
  const int la = lane & 31;
  const int hi = lane >> 5;
  const int lane8 = lane * 8;
  const int q0w = Q0 + 32 * wq;
  const int kmax = Kb + wq;              // this wave's diagonal kv-group
  const int mybase = h2 ? ha : 0;
  const int myn = min(ha, kmax - mybase + 1);   // groups this wave computes

  __shared__ __align__(16) u16 smem[16384];
  __shared__ float lM[4][32];

  // Q B-fragments, prescaled by 0.125*log2(e) (base-2 softmax domain)
  bf8 qf0, qf1, qf2, qf3;
  {
    const u16* qp = qkv + (size_t)(q0w + la) * 3072 + head * 64 + hi * 8;
    const float SC = 0.125f * 1.44269504088896340736f;
#define QLOAD(dst, kk) do {                                          \
      u16x8 v = *(const u16x8*)(qp + (kk) * 16);                     \
      u16x8 sv;                                                      \
      _Pragma("unroll") for (int e = 0; e < 8; ++e)                  \
        sv[e] = f2b(b2f(v[e]) * SC);                                 \
      dst = asbf8(sv);                                               \
    } while (0)
    QLOAD(qf0, 0); QLOAD(qf1, 1); QLOAD(qf2, 2); QLOAD(qf3, 3);
#undef QLOAD
  }

  const u16* Kg = Kf + (size_t)kh * 131072;
  const u16* Vg = Vf + (size_t)kh * 131072;

  f32x16 o0 = {}, o1 = {};
  float l_run = 0.f;

  if (myn > 0) STG(mybase);              // prologue: first group

  for (int i = 0; i < myn; ++i) {
    asm volatile("s_waitcnt vmcnt(0)" ::: "memory");   // group i landed
    __builtin_amdgcn_sched_barrier(0);
    const int bb = mybase + i;
    const u16* p_ = &smem[w * 4096 + lane8];
    bf8 K0 = asbf8(*(const u16x8*)(p_));
    bf8 K1 = asbf8(*(const u16x8*)(p_ + 512));
    bf8 K2 = asbf8(*(const u16x8*)(p_ + 1024));
    bf8 K3 = asbf8(*(const u16x8*)(p_ + 1536));
    bf8 V0 = asbf8(*(const u16x8*)(p_ + 2048));
    bf8 V1 = asbf8(*(const u16x8*)(p_ + 2560));
    bf8 V2 = asbf8(*(const u16x8*)(p_ + 3072));
    bf8 V3 = asbf8(*(const u16x8*)(p_ + 3584));
    asm volatile("s_waitcnt lgkmcnt(0)" ::: "memory"); // reads retired
    __builtin_amdgcn_sched_barrier(0);
    if (i + 1 < myn) STG(bb + 1);        // WAR-safe; latency hides in compute
    f32x16 s = {};
    __builtin_amdgcn_s_setprio(1);
    s = MFMA32(K0, qf0, s);
    s = MFMA32(K1, qf1, s);
    s = MFMA32(K2, qf2, s);
    s = MFMA32(K3, qf3, s);
    __builtin_amdgcn_s_setprio(0);
    if (bb == kmax) {                    // diagonal group: causal mask
#pragma unroll
      for (int r = 0; r < 16; ++r) {
        int kvr = bb * 32 + (r & 3) + 8 * (r >> 2) + 4 * hi;
        if (kvr > q0w + la) s[r] = -1e30f;
      }
    }
#pragma unroll
    for (int r = 0; r < 16; ++r) s[r] = ex2(s[r]);
    {
      float z0 = s[0] + s[1],   z1 = s[2] + s[3];
      float z2 = s[4] + s[5],   z3 = s[6] + s[7];
      float z4 = s[8] + s[9],   z5 = s[10] + s[11];
      float z6 = s[12] + s[13], z7 = s[14] + s[15];
      l_run += ((z0 + z1) + (z2 + z3)) + ((z4 + z5) + (z6 + z7));
    }
    u32 c0 = cvtpk(s[0], s[1]),   c1 = cvtpk(s[2], s[3]);
    u32 c2 = cvtpk(s[4], s[5]),   c3 = cvtpk(s[6], s[7]);
    u32 c4 = cvtpk(s[8], s[9]),   c5 = cvtpk(s[10], s[11]);
    u32 c6 = cvtpk(s[12], s[13]), c7 = cvtpk(s[14], s[15]);
    plswap(c0, c2); plswap(c1, c3); plswap(c4, c6); plswap(c5, c7);
    u32x4 t0; t0[0] = c0; t0[1] = c1; t0[2] = c2; t0[3] = c3;
    u32x4 t1; t1[0] = c4; t1[1] = c5; t1[2] = c6; t1[3] = c7;
    bf8 pa0 = __builtin_bit_cast(bf8, t0);
    bf8 pa1 = __builtin_bit_cast(bf8, t1);
    __builtin_amdgcn_s_setprio(1);
    o0 = MFMA32(pa0, V0, o0);
    o0 = MFMA32(pa1, V1, o0);
    o1 = MFMA32(pa0, V2, o1);
    o1 = MFMA32(pa1, V3, o1);
    __builtin_amdgcn_s_setprio(0);
  }

  __syncthreads();                       // all waves done with private slots

  {
    float lt = l_run + __shfl_xor(l_run, 32);
    if (lane < 32) lM[w][lane] = lt;
#pragma unroll
    for (int r = 0; r < 16; ++r) {
      int crow = (r & 3) + 8 * (r >> 2) + 4 * hi;
      smem[(w * 32 + crow) * 72 + la]      = f2b(o0[r]);
      smem[(w * 32 + crow) * 72 + la + 32] = f2b(o1[r]);
    }
  }
  __syncthreads();

#pragma unroll
  for (int it = 0; it < 2; ++it) {
    const int id = t + it * 256;
    const int q = id >> 3, d0 = (id & 7) * 8;
    const int wA = q >> 5, crow = q & 31;
    float inv = 1.0f / (lM[wA][crow] + lM[wA + 2][crow]);
    u16x8 a = *(const u16x8*)&smem[((wA)     * 32 + crow) * 72 + d0];
    u16x8 b = *(const u16x8*)&smem[((wA + 2) * 32 + crow) * 72 + d0];
    u16x8 outv;
#pragma unroll
    for (int j = 0; j < 8; ++j)
      outv[j] = f2b((b2f(a[j]) + b2f(b[j])) * inv);
    *(u16x8*)(aout + (size_t)(Q0 + q) * 2048 + head * 64 + d0) = outv;
  }
}

// ---------------- launch ----------------

extern "C" void kernel_launch(void* const* d_in, const int* in_sizes, int n_in,
                              void* d_out, int out_size, void* d_ws, size_t ws_size,
                              hipStream_t stream) {
  (void)in_sizes; (void)n_in; (void)out_size; (void)ws_size;
  const float* x  = (const float*)d_in[0];
  const float* wq = (const float*)d_in[1];
  const float* wk = (const float*)d_in[2];
  const float* wv = (const float*)d_in[3];
  const float* wo = (const float*)d_in[4];
  const float* cs = (const float*)d_in[5];
  const float* sn = (const float*)d_in[6];
  // d_in[7] = causal mask, implemented analytically

  u16* ws    = (u16*)d_ws;
  u16* xb    = ws;                         // [2048][2048] bf16 (later aout)
  u16* wqkvT = ws + 4194304;               // [3072][2048] bf16 (later Kf/Vf/op2)
  u16* qkv   = ws + 10485760;              // [2048][3072] bf16; QKV partial z=0 in place
  u16* woT   = ws + 16777216;              // [2048][2048] bf16
  u16* ext   = ws + 20971520;              // [2048][3072] bf16: QKV partial z=1
  u16* Kf    = wqkvT;                      // [8][64][4][2][32][8] after QKV gemm
  u16* Vf    = wqkvT + 1048576;
  u16* aout  = xb;
  u16* op0   = qkv;                        // out-proj partials (regions free)
  u16* op1   = ext;
  u16* op2   = wqkvT;                      // Kf/Vf dead after attn

  prep_all<<<6656, 256, 0, stream>>>(x, wq, wk, wv, wo, xb, wqkvT, woT);

  // QKV: [2048][3072], split-K x2 (768 blocks), BK=64
  gemm_sk<<<dim3(24, 16, 2), 256, 0, stream>>>(xb, wqkvT, qkv, ext, nullptr,
                                               3072, 2048, 1024);
  reduce_qkv<<<3072, 256, 0, stream>>>(qkv, ext, Kf, Vf, cs, sn);
  attn_fwd<<<dim3(32, 32), 256, 0, stream>>>(qkv, Kf, Vf, aout);
  // out-proj: [2048][2048], split-K x3 (768 blocks), KH=704/704/640
  gemm_sk<<<dim3(16, 16, 3), 256, 0, stream>>>(aout, woT, op0, op1, op2,
                                               2048, 2048, 704);
  reduce_out3<<<2048, 256, 0, stream>>>(op0, op1, op2, (float*)d_out);
}